// Round 2
// baseline (248.558 us; speedup 1.0000x reference)
//
#include <hip/hip_runtime.h>
#include <hip/hip_bf16.h>
#include <math.h>

// B=8, S=4096, D_IN=64, H=512 single-head attention, fp32 I/O (dtype-probed).
// scores = x (Wq Wk^T) x^T / sqrt(H); out = softmax(scores) x Wv + bv.
// Folded biases: qb[s]=x_s·(Wq bk)+bq·bk, kb[t]=x_t·(Wk bq); +bv passes thru.
// R9: LDS-pipe was the bottleneck (~60% busy, 1.05e7 conflict-cycles).
//  (a) V fragments now read DIRECTLY from global xT (per-batch 512KB is
//      L2-resident on its XCD via the blockIdx&7 swizzle) with 1-tile reg
//      prefetch — removes 4 LDS reads + 1 LDS write per wave-iter (m169).
//  (b) X tile staged with permuted rows tau(k)=(k&3)+4(k>>3)+16((k>>2)&1)
//      so frag reads hit rows l16 / 16+l16 -> 2-way bank aliasing (free)
//      instead of the 4-way conflict of rA-indexed reads (padding cannot
//      fix: 16B alignment forces stride=4n dwords, rows 8 apart collide).
//      A-row m still holds key 8*quad+r, so shuffle-free P is unchanged.

#define SS 4096
#define DD 64
#define HH 512

#define CSCALE ((float)(1.4426950408889634 * 0.04419417382415922))

typedef __bf16 bf16x8 __attribute__((ext_vector_type(8)));
typedef float  f32x4  __attribute__((ext_vector_type(4)));
typedef unsigned int u32x4 __attribute__((ext_vector_type(4)));

__device__ __forceinline__ float b2f(__hip_bfloat16 v) { return __bfloat162float(v); }

__device__ __forceinline__ f32x4 mfma16(bf16x8 a, bf16x8 b, f32x4 c) {
  return __builtin_amdgcn_mfma_f32_16x16x32_bf16(a, b, c, 0, 0, 0);
}

__device__ __forceinline__ unsigned pack2(float a, float b) {
  float2 f2; f2.x = a; f2.y = b;
  __hip_bfloat162 h2 = __float22bfloat162_rn(f2);   // a in low 16
  unsigned u; __builtin_memcpy(&u, &h2, 4);
  return u;
}

__device__ __forceinline__ float loadf(const void* p, size_t i, int isF32) {
  return isF32 ? ((const float*)p)[i] : b2f(((const __hip_bfloat16*)p)[i]);
}
__device__ __forceinline__ void load8f(const void* p, size_t i, int isF32, float* o) {
  if (isF32) {
    const float4 a = *(const float4*)((const float*)p + i);
    const float4 b = *(const float4*)((const float*)p + i + 4);
    o[0]=a.x; o[1]=a.y; o[2]=a.z; o[3]=a.w; o[4]=b.x; o[5]=b.y; o[6]=b.z; o[7]=b.w;
  } else {
    const bf16x8 v = *(const bf16x8*)((const __hip_bfloat16*)p + i);
#pragma unroll
    for (int k = 0; k < 8; ++k) { __hip_bfloat16 h; __builtin_memcpy(&h, ((const unsigned short*)&v) + k, 2); o[k] = b2f(h); }
  }
}

// ---------------- dtype probe (flag=1 -> fp32 inputs) ----------------------
__global__ void dtype_probe(const void* __restrict__ Wq, int* __restrict__ flag) {
  const unsigned short* h = (const unsigned short*)Wq;
  const int lane = threadIdx.x;
  unsigned int bits = ((unsigned int)h[lane * 2]) << 16;
  float v; __builtin_memcpy(&v, &bits, 4);
  v = fabsf(v);
  if (!isfinite(v) || v > 1e10f) v = 1e10f;
  for (int off = 1; off < 64; off <<= 1) v = fmaxf(v, __shfl_xor(v, off, 64));
  if (lane == 0) *flag = (v > 1e6f) ? 1 : 0;
}

// ---------------- prep: MT=(Wq Wk^T)^T bf16, u, w, c, wvT ------------------
__global__ __launch_bounds__(256) void prep_kernel(
    const void* __restrict__ Wq, const void* __restrict__ Wk,
    const void* __restrict__ Wv, const void* __restrict__ bq,
    const void* __restrict__ bk, __hip_bfloat16* __restrict__ MT,
    float* __restrict__ u, float* __restrict__ w_, float* __restrict__ c_,
    __hip_bfloat16* __restrict__ wvT, const int* __restrict__ flag) {
  const int t = threadIdx.x, blk = blockIdx.x;
  const int isF32 = *flag;
  if (blk < 64) {
    __shared__ float red[256];
    const int i = blk, j = t >> 2, part = t & 3;
    float acc = 0.f, aq[8], ak[8];
    for (int c = 0; c < 16; ++c) {
      load8f(Wq, (size_t)i * HH + part * 128 + c * 8, isF32, aq);
      load8f(Wk, (size_t)j * HH + part * 128 + c * 8, isF32, ak);
#pragma unroll
      for (int k = 0; k < 8; ++k) acc = fmaf(aq[k], ak[k], acc);
    }
    red[t] = acc;
    __syncthreads();
    if (t < 64)
      MT[t * 64 + i] = __float2bfloat16(red[t*4] + red[t*4+1] + red[t*4+2] + red[t*4+3]);
  } else if (blk == 64) {
    __shared__ float pu[256], pw[256], pc[64];
    const int i = t & 63, part = t >> 6;
    float au = 0.f, aw = 0.f, v1[8], v2[8];
    for (int c = 0; c < 16; ++c) {
      load8f(Wq, (size_t)i * HH + part * 128 + c * 8, isF32, v1);
      load8f(bk, part * 128 + c * 8, isF32, v2);
#pragma unroll
      for (int k = 0; k < 8; ++k) au = fmaf(v1[k], v2[k], au);
      load8f(Wk, (size_t)i * HH + part * 128 + c * 8, isF32, v1);
      load8f(bq, part * 128 + c * 8, isF32, v2);
#pragma unroll
      for (int k = 0; k < 8; ++k) aw = fmaf(v1[k], v2[k], aw);
    }
    pu[t] = au; pw[t] = aw;
    if (t < 64) {
      float s = 0.f;
      for (int e = 0; e < 8; ++e)
        s = fmaf(loadf(bq, t * 8 + e, isF32), loadf(bk, t * 8 + e, isF32), s);
      pc[t] = s;
    }
    __syncthreads();
    if (t < 64) {
      u[t]  = pu[t] + pu[t+64] + pu[t+128] + pu[t+192];
      w_[t] = pw[t] + pw[t+64] + pw[t+128] + pw[t+192];
    }
    if (t == 0) {
      float s = 0.f;
      for (int e = 0; e < 64; ++e) s += pc[e];
      *c_ = s;
    }
  } else {
    const int base = (blk - 65) * 2048 + t;
    for (int r = 0; r < 8; ++r) {
      const int e = base + r * 256;          // e = h*64 + d
      const int h = e >> 6, d = e & 63;
      wvT[e] = __float2bfloat16(loadf(Wv, (size_t)d * HH + h, isF32));
    }
  }
}

// ---------------- proj: xc, y = x*M (MFMA), qb/kb, xT ----------------------
__global__ __launch_bounds__(256) void proj_kernel(
    const void* __restrict__ xraw, const __hip_bfloat16* __restrict__ MT,
    const float* __restrict__ u, const float* __restrict__ w_,
    const float* __restrict__ c_, __hip_bfloat16* __restrict__ xc,
    __hip_bfloat16* __restrict__ y, float* __restrict__ qb,
    float* __restrict__ kb, __hip_bfloat16* __restrict__ xT,
    const int* __restrict__ flag) {
  __shared__ __hip_bfloat16 xs[64 * 72];
  __shared__ __hip_bfloat16 Ms[64 * 72];   // MT staged: Ms[ycol][d]
  __shared__ float us[64], wl[64];
  __shared__ float cs;

  const int t = threadIdx.x;
  const int isF32 = *flag;
  {
    const int r = t >> 2, cb = (t & 3) * 16;
    *(bf16x8*)(&Ms[r * 72 + cb])     = *(const bf16x8*)(MT + r * 64 + cb);
    *(bf16x8*)(&Ms[r * 72 + cb + 8]) = *(const bf16x8*)(MT + r * 64 + cb + 8);
  }
  if (t < 64) { us[t] = u[t]; wl[t] = w_[t]; }
  if (t == 0) cs = *c_;

  const int b = blockIdx.x & 7;
  const int sbase = (blockIdx.x >> 3) * 64;
  const int rbase = b * SS + sbase;

  for (int i = 0; i < 2; ++i) {
    const int e = i * 256 + t;
    const int row = e >> 3, col = (e & 7) * 8;
    float v[8];
    load8f(xraw, (size_t)(rbase + row) * DD + col, isF32, v);
    __hip_bfloat16* dp = xs + row * 72 + col;
#pragma unroll
    for (int k = 0; k < 8; ++k) dp[k] = __float2bfloat16(v[k]);
  }
  __syncthreads();

  const int wv = t >> 6, lane = t & 63;
  const int l16 = lane & 15, quad = lane >> 4;
  // y tile: wave = 16 rows; A[m=row][k=d]
  const bf16x8 A0 = *(const bf16x8*)(&xs[(wv * 16 + l16) * 72 + quad * 8]);
  const bf16x8 A1 = *(const bf16x8*)(&xs[(wv * 16 + l16) * 72 + 32 + quad * 8]);
#pragma unroll
  for (int nt = 0; nt < 4; ++nt) {
    const bf16x8 B0 = *(const bf16x8*)(&Ms[(nt * 16 + l16) * 72 + quad * 8]);
    const bf16x8 B1 = *(const bf16x8*)(&Ms[(nt * 16 + l16) * 72 + 32 + quad * 8]);
    f32x4 C = (f32x4){0.f, 0.f, 0.f, 0.f};
    C = mfma16(A0, B0, C);
    C = mfma16(A1, B1, C);
#pragma unroll
    for (int r = 0; r < 4; ++r)
      y[(size_t)(rbase + wv * 16 + quad * 4 + r) * DD + nt * 16 + l16] =
          __float2bfloat16(C[r]);
  }
  if (t < 64) {
    float qa = 0.f, ka = 0.f;
    for (int d = 0; d < 64; ++d) {
      const float xv = b2f(xs[t * 72 + d]);
      qa = fmaf(xv, us[d], qa);
      ka = fmaf(xv, wl[d], ka);
    }
    qb[rbase + t] = (qa + cs) * CSCALE;
    kb[rbase + t] = ka * CSCALE;
  }
  for (int i = 0; i < 2; ++i) {
    const int e = i * 256 + t;
    const int row = e >> 3, col = (e & 7) * 8;
    *(bf16x8*)(xc + (size_t)(rbase + row) * DD + col) = *(const bf16x8*)(xs + row * 72 + col);
  }
  for (int i = 0; i < 16; ++i) {
    const int d = i * 4 + (t >> 6);
    const int sl = t & 63;
    xT[((size_t)b * DD + d) * SS + sbase + sl] = xs[sl * 72 + d];
  }
}

// ---------------- attn: flash loop, V from global (L2), permuted X rows ----
__global__ __launch_bounds__(256) void attn_kernel(
    const __hip_bfloat16* __restrict__ x,
    const __hip_bfloat16* __restrict__ y,
    const float* __restrict__ qb, const float* __restrict__ kb,
    const __hip_bfloat16* __restrict__ xT,
    const __hip_bfloat16* __restrict__ wvT,
    const void* __restrict__ bv_raw,
    void* __restrict__ out_raw, const int* __restrict__ flag) {
  __shared__ __hip_bfloat16 xs[2][32 * 72];    // 9.2 KB (double-buffered X tile)
  __shared__ float kbl[SS];                    // 16 KB
  const int tid = threadIdx.x;
  const int wv = tid >> 6, lane = tid & 63;
  const int l16 = lane & 15, quad = lane >> 4;
  const int b = blockIdx.x & 7;               // batch round-robin over XCDs
  const int qt = (blockIdx.x >> 3) * 4 + wv;  // q-tile within batch
  const size_t rowq = ((size_t)b << 12) + ((size_t)qt << 4);
  const int isF32 = *flag;

  const __hip_bfloat16* xb  = x  + ((size_t)b * SS) * DD;
  const __hip_bfloat16* xTb = xT + ((size_t)b * DD) * SS;
  const float* kbb = kb + ((size_t)b * SS);

  // Y frags (B-operand of S^T = X·Y^T): lane holds y[q=l16][quad*8+j]
  const __hip_bfloat16* yp = y + (rowq + l16) * DD + quad * 8;
  const bf16x8 Ylo = *(const bf16x8*)yp;
  const bf16x8 Yhi = *(const bf16x8*)(yp + 32);
  const float qbl = qb[rowq + l16];           // per-lane query bias (pre-scaled)

  // X staging: thread stages key row sxr into PERMUTED LDS row tau(sxr):
  // tau(k) = (k&3) + 4*(k>>3) + 16*((k>>2)&1). Frag reads then hit rows
  // l16 (keys 8q+r) and 16+l16 (keys 8q+4+r): 2-way bank aliasing only.
  const int sxr = tid >> 3, sxc = (tid & 7) * 8;
  const int taur = (sxr & 3) + ((sxr >> 3) << 2) + (((sxr >> 2) & 1) << 4);
  const __hip_bfloat16* gx = xb + (size_t)sxr * DD + sxc;
  __hip_bfloat16* const stp = &xs[0][0] + taur * 72 + sxc;   // buf 0 slot
  const int bufel = 32 * 72;

  // V fragment pointers (direct global reads of L2-resident xT):
  // PV B-frag n-block: lane (quad,l16) needs xT[d=16n+l16][kt + quad*8..+7]
  const __hip_bfloat16* gv = xTb + (size_t)l16 * SS + quad * 8;

  // stage whole-batch kb into LDS (4 x f32x4 per thread, coalesced)
#pragma unroll
  for (int j = 0; j < 4; ++j) {
    const int c = j * 256 + tid;               // chunk of 4 floats
    *(f32x4*)(&kbl[c * 4]) = *(const f32x4*)(kbb + c * 4);
  }

  // prologue: X tile 0 -> buf 0; X tile 1 -> regs; V tile 0 -> regs
  bf16x8 nx = *(const bf16x8*)gx;
  *(bf16x8*)stp = nx;
  nx = *(const bf16x8*)(gx + 32 * DD);
  bf16x8 V0n = *(const bf16x8*)(gv);
  bf16x8 V1n = *(const bf16x8*)(gv + 16 * SS);
  bf16x8 V2n = *(const bf16x8*)(gv + 32 * SS);
  bf16x8 V3n = *(const bf16x8*)(gv + 48 * SS);
  __syncthreads();

  bf16x8 onesb;
#pragma unroll
  for (int j = 0; j < 8; ++j) onesb[j] = (__bf16)1.0f;

  f32x4 O[4];
#pragma unroll
  for (int n = 0; n < 4; ++n) O[n] = (f32x4){0.f, 0.f, 0.f, 0.f};
  f32x4 Ol = (f32x4){0.f, 0.f, 0.f, 0.f};

  for (int kt = 0; kt < SS; kt += 32) {
    const int p = (kt >> 5) & 1, np = p ^ 1;
    // write X tile kt+32 (in regs) to buf np; start X load for tile kt+64
    if (kt + 32 < SS) {
      *(bf16x8*)(stp + np * bufel) = nx;
      if (kt + 64 < SS) nx = *(const bf16x8*)(gx + (size_t)(kt + 64) * DD);
    }
    // rotate V prefetch regs; issue V loads for next tile (clamped)
    const bf16x8 V0 = V0n, V1 = V1n, V2 = V2n, V3 = V3n;
    const int ktn = (kt + 32 < SS) ? (kt + 32) : 0;
    V0n = *(const bf16x8*)(gv + ktn);
    V1n = *(const bf16x8*)(gv + 16 * SS + ktn);
    V2n = *(const bf16x8*)(gv + 32 * SS + ktn);
    V3n = *(const bf16x8*)(gv + 48 * SS + ktn);

    // X frags from buf p at permuted rows: row l16 holds key 8*(l16>>2)+(l16&3),
    // row 16+l16 holds that +4 — conflict-free (2-way) reads.
    const bf16x8 B00 = *(const bf16x8*)(&xs[p][l16 * 72 + quad * 8]);
    const bf16x8 B01 = *(const bf16x8*)(&xs[p][l16 * 72 + 32 + quad * 8]);
    const bf16x8 B10 = *(const bf16x8*)(&xs[p][(16 + l16) * 72 + quad * 8]);
    const bf16x8 B11 = *(const bf16x8*)(&xs[p][(16 + l16) * 72 + 32 + quad * 8]);

    // S^T: C-layout lane (quad,l16) reg r = (key 8q+r | 8q+4+r, query l16)
    f32x4 S0 = (f32x4){0.f, 0.f, 0.f, 0.f};
    f32x4 S1 = (f32x4){0.f, 0.f, 0.f, 0.f};
    S0 = mfma16(B00, Ylo, S0);
    S0 = mfma16(B01, Yhi, S0);
    S1 = mfma16(B10, Ylo, S1);
    S1 = mfma16(B11, Yhi, S1);

    const f32x4 kb0 = *(const f32x4*)(&kbl[kt + quad * 8]);        // keys 8q..8q+3
    const f32x4 kb1 = *(const f32x4*)(&kbl[kt + quad * 8 + 4]);    // keys 8q+4..8q+7

    float p0[4], p1[4];
#pragma unroll
    for (int r = 0; r < 4; ++r) {
      p0[r] = __builtin_amdgcn_exp2f(fmaf(S0[r], CSCALE, qbl + kb0[r]));
      p1[r] = __builtin_amdgcn_exp2f(fmaf(S1[r], CSCALE, qbl + kb1[r]));
    }
    // direct PV A-frag assembly: keys 8q+0..7 for query l16, in order
    u32x4 R;
    R[0] = pack2(p0[0], p0[1]);
    R[1] = pack2(p0[2], p0[3]);
    R[2] = pack2(p1[0], p1[1]);
    R[3] = pack2(p1[2], p1[3]);
    bf16x8 Pf;
    __builtin_memcpy(&Pf, &R, 16);

    O[0] = mfma16(Pf, V0, O[0]);
    O[1] = mfma16(Pf, V1, O[1]);
    O[2] = mfma16(Pf, V2, O[2]);
    O[3] = mfma16(Pf, V3, O[3]);
    Ol = mfma16(Pf, onesb, Ol);   // row-sums l

    __syncthreads();  // buf np fully written & buf p fully consumed
  }

  // normalize; out-projection out[16x512] = (O/l)[16x64] @ Wv + bv
  float inv_l[4];
#pragma unroll
  for (int r = 0; r < 4; ++r)
    inv_l[r] = (Ol[r] > 0.f) ? 1.0f / Ol[r] : 0.f;
  __hip_bfloat16* pl = &xs[0][0] + wv * 1152;   // reuse staging LDS (16x72)
#pragma unroll
  for (int n = 0; n < 4; ++n)
#pragma unroll
    for (int r = 0; r < 4; ++r) {
      const int row = quad * 4 + r;
      pl[row * 72 + n * 16 + l16] = __float2bfloat16(O[n][r] * inv_l[r]);
    }
  __syncthreads();
  const bf16x8 Alo = *(const bf16x8*)(pl + l16 * 72 + quad * 8);
  const bf16x8 Ahi = *(const bf16x8*)(pl + l16 * 72 + 32 + quad * 8);

  float* outf = (float*)out_raw;
  __hip_bfloat16* outb = (__hip_bfloat16*)out_raw;
#pragma unroll 4
  for (int ht = 0; ht < 32; ++ht) {
    const __hip_bfloat16* wp = wvT + (size_t)(ht * 16 + l16) * DD + quad * 8;
    const bf16x8 Wlo = *(const bf16x8*)wp;
    const bf16x8 Whi = *(const bf16x8*)(wp + 32);
    f32x4 C = (f32x4){0.f, 0.f, 0.f, 0.f};
    C = mfma16(Alo, Wlo, C);
    C = mfma16(Ahi, Whi, C);
    const float bvv = loadf(bv_raw, ht * 16 + l16, isF32);
#pragma unroll
    for (int r = 0; r < 4; ++r) {
      const size_t oidx = (rowq + quad * 4 + r) * HH + ht * 16 + l16;
      const float val = C[r] + bvv;
      if (isF32) outf[oidx] = val;
      else       outb[oidx] = __float2bfloat16(val);
    }
  }
}

// ---------------- launcher --------------------------------------------------
extern "C" void kernel_launch(void* const* d_in, const int* in_sizes, int n_in,
                              void* d_out, int out_size, void* d_ws,
                              size_t ws_size, hipStream_t stream) {
  char* ws = (char*)d_ws;
  int*   flag = (int*)(ws + 0);
  __hip_bfloat16* MT = (__hip_bfloat16*)(ws + 1024);       // 8 KB
  float* u    = (float*)(ws + 9216);
  float* w_   = (float*)(ws + 9728);
  float* c_   = (float*)(ws + 10240);
  __hip_bfloat16* wvT = (__hip_bfloat16*)(ws + 32768);     // 64 KB
  __hip_bfloat16* xc  = (__hip_bfloat16*)(ws + 131072);    // 4 MB
  __hip_bfloat16* y   = (__hip_bfloat16*)(ws + 4325376);   // 4 MB
  float* qb = (float*)(ws + 8519680);                       // 128 KB
  float* kb = (float*)(ws + 8650752);                       // 128 KB
  __hip_bfloat16* xT = (__hip_bfloat16*)(ws + 8781824);    // 4 MB
  // total ws use: ~12.4 MB

  dtype_probe<<<1, 64, 0, stream>>>(d_in[1], flag);
  prep_kernel<<<81, 256, 0, stream>>>(d_in[1], d_in[3], d_in[5], d_in[2],
                                      d_in[4], MT, u, w_, c_, wvT, flag);
  proj_kernel<<<512, 256, 0, stream>>>(d_in[0], MT, u, w_, c_, xc, y, qb, kb,
                                       xT, flag);
  attn_kernel<<<512, 256, 0, stream>>>(xc, y, qb, kb, xT, wvT, d_in[6], d_out,
                                       flag);
}

// Round 3
// 189.323 us; speedup vs baseline: 1.3129x; 1.3129x over previous
//
#include <hip/hip_runtime.h>
#include <hip/hip_bf16.h>
#include <math.h>

// B=8, S=4096, D_IN=64, H=512 single-head attention, fp32 I/O (dtype-probed).
// scores = x (Wq Wk^T) x^T / sqrt(H); out = softmax(scores) x Wv + bv.
// Folded biases: qb[s]=x_s·(Wq bk)+bq·bk, kb[t]=x_t·(Wk bq); +bv passes thru.
// R10 = R8 structure + R9's conflict fix only.
//  - V back in LDS (R9 post-mortem: per-wave scattered global V loads made
//    the loop VMEM-latency-bound, 102->160us; LDS staging does the 16-row
//    scatter once per block, latency hidden 2 tiles deep).
//  - X tile staged at PERMUTED rows tau(k)=(k&3)+4*(k>>3)+16*((k>>2)&1) so
//    frag reads hit rows l16 / 16+l16 -> 2-way bank aliasing (free, m136)
//    instead of 4-way (verified: conflicts 1.05e7->4.2e6 in R9).
//    tau(8h+r)=4h+r=l16, tau(8h+4+r)=16+l16 -> lane (quad,l16) still holds
//    keys 8*quad+r / +4: shuffle-free P layout unchanged.

#define SS 4096
#define DD 64
#define HH 512

#define CSCALE ((float)(1.4426950408889634 * 0.04419417382415922))

typedef __bf16 bf16x8 __attribute__((ext_vector_type(8)));
typedef float  f32x4  __attribute__((ext_vector_type(4)));
typedef unsigned int u32x4 __attribute__((ext_vector_type(4)));

__device__ __forceinline__ float b2f(__hip_bfloat16 v) { return __bfloat162float(v); }

__device__ __forceinline__ f32x4 mfma16(bf16x8 a, bf16x8 b, f32x4 c) {
  return __builtin_amdgcn_mfma_f32_16x16x32_bf16(a, b, c, 0, 0, 0);
}

__device__ __forceinline__ unsigned pack2(float a, float b) {
  float2 f2; f2.x = a; f2.y = b;
  __hip_bfloat162 h2 = __float22bfloat162_rn(f2);   // a in low 16
  unsigned u; __builtin_memcpy(&u, &h2, 4);
  return u;
}

__device__ __forceinline__ float loadf(const void* p, size_t i, int isF32) {
  return isF32 ? ((const float*)p)[i] : b2f(((const __hip_bfloat16*)p)[i]);
}
__device__ __forceinline__ void load8f(const void* p, size_t i, int isF32, float* o) {
  if (isF32) {
    const float4 a = *(const float4*)((const float*)p + i);
    const float4 b = *(const float4*)((const float*)p + i + 4);
    o[0]=a.x; o[1]=a.y; o[2]=a.z; o[3]=a.w; o[4]=b.x; o[5]=b.y; o[6]=b.z; o[7]=b.w;
  } else {
    const bf16x8 v = *(const bf16x8*)((const __hip_bfloat16*)p + i);
#pragma unroll
    for (int k = 0; k < 8; ++k) { __hip_bfloat16 h; __builtin_memcpy(&h, ((const unsigned short*)&v) + k, 2); o[k] = b2f(h); }
  }
}

// ---------------- dtype probe (flag=1 -> fp32 inputs) ----------------------
__global__ void dtype_probe(const void* __restrict__ Wq, int* __restrict__ flag) {
  const unsigned short* h = (const unsigned short*)Wq;
  const int lane = threadIdx.x;
  unsigned int bits = ((unsigned int)h[lane * 2]) << 16;
  float v; __builtin_memcpy(&v, &bits, 4);
  v = fabsf(v);
  if (!isfinite(v) || v > 1e10f) v = 1e10f;
  for (int off = 1; off < 64; off <<= 1) v = fmaxf(v, __shfl_xor(v, off, 64));
  if (lane == 0) *flag = (v > 1e6f) ? 1 : 0;
}

// ---------------- prep: MT=(Wq Wk^T)^T bf16, u, w, c, wvT ------------------
__global__ __launch_bounds__(256) void prep_kernel(
    const void* __restrict__ Wq, const void* __restrict__ Wk,
    const void* __restrict__ Wv, const void* __restrict__ bq,
    const void* __restrict__ bk, __hip_bfloat16* __restrict__ MT,
    float* __restrict__ u, float* __restrict__ w_, float* __restrict__ c_,
    __hip_bfloat16* __restrict__ wvT, const int* __restrict__ flag) {
  const int t = threadIdx.x, blk = blockIdx.x;
  const int isF32 = *flag;
  if (blk < 64) {
    __shared__ float red[256];
    const int i = blk, j = t >> 2, part = t & 3;
    float acc = 0.f, aq[8], ak[8];
    for (int c = 0; c < 16; ++c) {
      load8f(Wq, (size_t)i * HH + part * 128 + c * 8, isF32, aq);
      load8f(Wk, (size_t)j * HH + part * 128 + c * 8, isF32, ak);
#pragma unroll
      for (int k = 0; k < 8; ++k) acc = fmaf(aq[k], ak[k], acc);
    }
    red[t] = acc;
    __syncthreads();
    if (t < 64)
      MT[t * 64 + i] = __float2bfloat16(red[t*4] + red[t*4+1] + red[t*4+2] + red[t*4+3]);
  } else if (blk == 64) {
    __shared__ float pu[256], pw[256], pc[64];
    const int i = t & 63, part = t >> 6;
    float au = 0.f, aw = 0.f, v1[8], v2[8];
    for (int c = 0; c < 16; ++c) {
      load8f(Wq, (size_t)i * HH + part * 128 + c * 8, isF32, v1);
      load8f(bk, part * 128 + c * 8, isF32, v2);
#pragma unroll
      for (int k = 0; k < 8; ++k) au = fmaf(v1[k], v2[k], au);
      load8f(Wk, (size_t)i * HH + part * 128 + c * 8, isF32, v1);
      load8f(bq, part * 128 + c * 8, isF32, v2);
#pragma unroll
      for (int k = 0; k < 8; ++k) aw = fmaf(v1[k], v2[k], aw);
    }
    pu[t] = au; pw[t] = aw;
    if (t < 64) {
      float s = 0.f;
      for (int e = 0; e < 8; ++e)
        s = fmaf(loadf(bq, t * 8 + e, isF32), loadf(bk, t * 8 + e, isF32), s);
      pc[t] = s;
    }
    __syncthreads();
    if (t < 64) {
      u[t]  = pu[t] + pu[t+64] + pu[t+128] + pu[t+192];
      w_[t] = pw[t] + pw[t+64] + pw[t+128] + pw[t+192];
    }
    if (t == 0) {
      float s = 0.f;
      for (int e = 0; e < 64; ++e) s += pc[e];
      *c_ = s;
    }
  } else {
    const int base = (blk - 65) * 2048 + t;
    for (int r = 0; r < 8; ++r) {
      const int e = base + r * 256;          // e = h*64 + d
      const int h = e >> 6, d = e & 63;
      wvT[e] = __float2bfloat16(loadf(Wv, (size_t)d * HH + h, isF32));
    }
  }
}

// ---------------- proj: xc, y = x*M (MFMA), qb/kb, xT ----------------------
__global__ __launch_bounds__(256) void proj_kernel(
    const void* __restrict__ xraw, const __hip_bfloat16* __restrict__ MT,
    const float* __restrict__ u, const float* __restrict__ w_,
    const float* __restrict__ c_, __hip_bfloat16* __restrict__ xc,
    __hip_bfloat16* __restrict__ y, float* __restrict__ qb,
    float* __restrict__ kb, __hip_bfloat16* __restrict__ xT,
    const int* __restrict__ flag) {
  __shared__ __hip_bfloat16 xs[64 * 72];
  __shared__ __hip_bfloat16 Ms[64 * 72];   // MT staged: Ms[ycol][d]
  __shared__ float us[64], wl[64];
  __shared__ float cs;

  const int t = threadIdx.x;
  const int isF32 = *flag;
  {
    const int r = t >> 2, cb = (t & 3) * 16;
    *(bf16x8*)(&Ms[r * 72 + cb])     = *(const bf16x8*)(MT + r * 64 + cb);
    *(bf16x8*)(&Ms[r * 72 + cb + 8]) = *(const bf16x8*)(MT + r * 64 + cb + 8);
  }
  if (t < 64) { us[t] = u[t]; wl[t] = w_[t]; }
  if (t == 0) cs = *c_;

  const int b = blockIdx.x & 7;
  const int sbase = (blockIdx.x >> 3) * 64;
  const int rbase = b * SS + sbase;

  for (int i = 0; i < 2; ++i) {
    const int e = i * 256 + t;
    const int row = e >> 3, col = (e & 7) * 8;
    float v[8];
    load8f(xraw, (size_t)(rbase + row) * DD + col, isF32, v);
    __hip_bfloat16* dp = xs + row * 72 + col;
#pragma unroll
    for (int k = 0; k < 8; ++k) dp[k] = __float2bfloat16(v[k]);
  }
  __syncthreads();

  const int wv = t >> 6, lane = t & 63;
  const int l16 = lane & 15, quad = lane >> 4;
  // y tile: wave = 16 rows; A[m=row][k=d]
  const bf16x8 A0 = *(const bf16x8*)(&xs[(wv * 16 + l16) * 72 + quad * 8]);
  const bf16x8 A1 = *(const bf16x8*)(&xs[(wv * 16 + l16) * 72 + 32 + quad * 8]);
#pragma unroll
  for (int nt = 0; nt < 4; ++nt) {
    const bf16x8 B0 = *(const bf16x8*)(&Ms[(nt * 16 + l16) * 72 + quad * 8]);
    const bf16x8 B1 = *(const bf16x8*)(&Ms[(nt * 16 + l16) * 72 + 32 + quad * 8]);
    f32x4 C = (f32x4){0.f, 0.f, 0.f, 0.f};
    C = mfma16(A0, B0, C);
    C = mfma16(A1, B1, C);
#pragma unroll
    for (int r = 0; r < 4; ++r)
      y[(size_t)(rbase + wv * 16 + quad * 4 + r) * DD + nt * 16 + l16] =
          __float2bfloat16(C[r]);
  }
  if (t < 64) {
    float qa = 0.f, ka = 0.f;
    for (int d = 0; d < 64; ++d) {
      const float xv = b2f(xs[t * 72 + d]);
      qa = fmaf(xv, us[d], qa);
      ka = fmaf(xv, wl[d], ka);
    }
    qb[rbase + t] = (qa + cs) * CSCALE;
    kb[rbase + t] = ka * CSCALE;
  }
  for (int i = 0; i < 2; ++i) {
    const int e = i * 256 + t;
    const int row = e >> 3, col = (e & 7) * 8;
    *(bf16x8*)(xc + (size_t)(rbase + row) * DD + col) = *(const bf16x8*)(xs + row * 72 + col);
  }
  for (int i = 0; i < 16; ++i) {
    const int d = i * 4 + (t >> 6);
    const int sl = t & 63;
    xT[((size_t)b * DD + d) * SS + sbase + sl] = xs[sl * 72 + d];
  }
}

// ---------------- attn: LDS-staged flash, permuted X rows, shuffle-free P --
__global__ __launch_bounds__(256) void attn_kernel(
    const __hip_bfloat16* __restrict__ x,
    const __hip_bfloat16* __restrict__ y,
    const float* __restrict__ qb, const float* __restrict__ kb,
    const __hip_bfloat16* __restrict__ xT,
    const __hip_bfloat16* __restrict__ wvT,
    const void* __restrict__ bv_raw,
    void* __restrict__ out_raw, const int* __restrict__ flag) {
  __shared__ __hip_bfloat16 xs[2][32 * 72];    // 9.2 KB
  __shared__ __hip_bfloat16 vsm[2][64 * 40];   // 10.2 KB
  __shared__ float kbl[SS];                    // 16 KB
  const int tid = threadIdx.x;
  const int wv = tid >> 6, lane = tid & 63;
  const int l16 = lane & 15, quad = lane >> 4;
  const int b = blockIdx.x & 7;               // batch round-robin over XCDs
  const int qt = (blockIdx.x >> 3) * 4 + wv;  // q-tile within batch
  const size_t rowq = ((size_t)b << 12) + ((size_t)qt << 4);
  const int isF32 = *flag;

  const __hip_bfloat16* xb  = x  + ((size_t)b * SS) * DD;
  const __hip_bfloat16* xTb = xT + ((size_t)b * DD) * SS;
  const float* kbb = kb + ((size_t)b * SS);

  // Y frags (B-operand of S^T = X·Y^T): lane holds y[q=l16][quad*8+j]
  const __hip_bfloat16* yp = y + (rowq + l16) * DD + quad * 8;
  const bf16x8 Ylo = *(const bf16x8*)yp;
  const bf16x8 Yhi = *(const bf16x8*)(yp + 32);
  const float qbl = qb[rowq + l16];           // per-lane query bias (pre-scaled)

  // staging assignment (block-wide, 256 threads); X rows go to PERMUTED
  // LDS row tau(sxr) so frag reads are rows l16 / 16+l16 (2-way, free).
  const int sxr = tid >> 3, sxc = (tid & 7) * 8;   // x-tile: key 0..31, col 0..56
  const int taur = (sxr & 3) + ((sxr >> 3) << 2) + (((sxr >> 2) & 1) << 4);
  const int svd = tid >> 2, svc = (tid & 3) * 8;   // v-tile: d 0..63, key-col 0..24
  const __hip_bfloat16* gx = xb + (size_t)sxr * DD + sxc;
  const __hip_bfloat16* gv = xTb + (size_t)svd * SS + svc;

  // stage whole-batch kb into LDS (4 x f32x4 per thread, coalesced)
#pragma unroll
  for (int j = 0; j < 4; ++j) {
    const int c = j * 256 + tid;               // chunk of 4 floats
    *(f32x4*)(&kbl[c * 4]) = *(const f32x4*)(kbb + c * 4);
  }

  // prologue: tile 0 -> buf 0; tile 1 -> regs
  bf16x8 nx = *(const bf16x8*)gx;
  bf16x8 nv = *(const bf16x8*)gv;
  *(bf16x8*)(&xs[0][taur * 72 + sxc]) = nx;
  *(bf16x8*)(&vsm[0][svd * 40 + svc]) = nv;
  nx = *(const bf16x8*)(gx + 32 * DD);
  nv = *(const bf16x8*)(gv + 32);
  __syncthreads();

  bf16x8 onesb;
#pragma unroll
  for (int j = 0; j < 8; ++j) onesb[j] = (__bf16)1.0f;

  f32x4 O[4];
#pragma unroll
  for (int n = 0; n < 4; ++n) O[n] = (f32x4){0.f, 0.f, 0.f, 0.f};
  f32x4 Ol = (f32x4){0.f, 0.f, 0.f, 0.f};

  for (int kt = 0; kt < SS; kt += 32) {
    const int p = (kt >> 5) & 1, np = p ^ 1;
    // write tile kt+32 (in regs) to buf np; start loads for tile kt+64
    if (kt + 32 < SS) {
      *(bf16x8*)(&xs[np][taur * 72 + sxc]) = nx;
      *(bf16x8*)(&vsm[np][svd * 40 + svc]) = nv;
      if (kt + 64 < SS) {
        nx = *(const bf16x8*)(gx + (size_t)(kt + 64) * DD);
        nv = *(const bf16x8*)(gv + (kt + 64));
      }
    }

    // X frags from buf p at permuted rows: row l16 holds key 8*(l16>>2)+(l16&3),
    // row 16+l16 holds that +4 — 2-way bank aliasing only (free).
    const bf16x8 B00 = *(const bf16x8*)(&xs[p][l16 * 72 + quad * 8]);
    const bf16x8 B01 = *(const bf16x8*)(&xs[p][l16 * 72 + 32 + quad * 8]);
    const bf16x8 B10 = *(const bf16x8*)(&xs[p][(16 + l16) * 72 + quad * 8]);
    const bf16x8 B11 = *(const bf16x8*)(&xs[p][(16 + l16) * 72 + 32 + quad * 8]);
    const bf16x8 V0 = *(const bf16x8*)(&vsm[p][l16 * 40 + quad * 8]);
    const bf16x8 V1 = *(const bf16x8*)(&vsm[p][(16 + l16) * 40 + quad * 8]);
    const bf16x8 V2 = *(const bf16x8*)(&vsm[p][(32 + l16) * 40 + quad * 8]);
    const bf16x8 V3 = *(const bf16x8*)(&vsm[p][(48 + l16) * 40 + quad * 8]);

    // S^T: C-layout lane (quad,l16) reg r = (key 8q+r | 8q+4+r, query l16)
    f32x4 S0 = (f32x4){0.f, 0.f, 0.f, 0.f};
    f32x4 S1 = (f32x4){0.f, 0.f, 0.f, 0.f};
    S0 = mfma16(B00, Ylo, S0);
    S0 = mfma16(B01, Yhi, S0);
    S1 = mfma16(B10, Ylo, S1);
    S1 = mfma16(B11, Yhi, S1);

    const f32x4 kb0 = *(const f32x4*)(&kbl[kt + quad * 8]);        // keys 8q..8q+3
    const f32x4 kb1 = *(const f32x4*)(&kbl[kt + quad * 8 + 4]);    // keys 8q+4..8q+7

    float p0[4], p1[4];
#pragma unroll
    for (int r = 0; r < 4; ++r) {
      p0[r] = __builtin_amdgcn_exp2f(fmaf(S0[r], CSCALE, qbl + kb0[r]));
      p1[r] = __builtin_amdgcn_exp2f(fmaf(S1[r], CSCALE, qbl + kb1[r]));
    }
    // direct PV A-frag assembly: keys 8q+0..7 for query l16, in order
    u32x4 R;
    R[0] = pack2(p0[0], p0[1]);
    R[1] = pack2(p0[2], p0[3]);
    R[2] = pack2(p1[0], p1[1]);
    R[3] = pack2(p1[2], p1[3]);
    bf16x8 Pf;
    __builtin_memcpy(&Pf, &R, 16);

    O[0] = mfma16(Pf, V0, O[0]);
    O[1] = mfma16(Pf, V1, O[1]);
    O[2] = mfma16(Pf, V2, O[2]);
    O[3] = mfma16(Pf, V3, O[3]);
    Ol = mfma16(Pf, onesb, Ol);   // row-sums l

    __syncthreads();  // buf np fully written & buf p fully consumed
  }

  // normalize; out-projection out[16x512] = (O/l)[16x64] @ Wv + bv
  float inv_l[4];
#pragma unroll
  for (int r = 0; r < 4; ++r)
    inv_l[r] = (Ol[r] > 0.f) ? 1.0f / Ol[r] : 0.f;
  __hip_bfloat16* pl = &xs[0][0] + wv * 1152;   // reuse staging LDS (16x72)
#pragma unroll
  for (int n = 0; n < 4; ++n)
#pragma unroll
    for (int r = 0; r < 4; ++r) {
      const int row = quad * 4 + r;
      pl[row * 72 + n * 16 + l16] = __float2bfloat16(O[n][r] * inv_l[r]);
    }
  __syncthreads();
  const bf16x8 Alo = *(const bf16x8*)(pl + l16 * 72 + quad * 8);
  const bf16x8 Ahi = *(const bf16x8*)(pl + l16 * 72 + 32 + quad * 8);

  float* outf = (float*)out_raw;
  __hip_bfloat16* outb = (__hip_bfloat16*)out_raw;
#pragma unroll 4
  for (int ht = 0; ht < 32; ++ht) {
    const __hip_bfloat16* wp = wvT + (size_t)(ht * 16 + l16) * DD + quad * 8;
    const bf16x8 Wlo = *(const bf16x8*)wp;
    const bf16x8 Whi = *(const bf16x8*)(wp + 32);
    f32x4 C = (f32x4){0.f, 0.f, 0.f, 0.f};
    C = mfma16(Alo, Wlo, C);
    C = mfma16(Ahi, Whi, C);
    const float bvv = loadf(bv_raw, ht * 16 + l16, isF32);
#pragma unroll
    for (int r = 0; r < 4; ++r) {
      const size_t oidx = (rowq + quad * 4 + r) * HH + ht * 16 + l16;
      const float val = C[r] + bvv;
      if (isF32) outf[oidx] = val;
      else       outb[oidx] = __float2bfloat16(val);
    }
  }
}

// ---------------- launcher --------------------------------------------------
extern "C" void kernel_launch(void* const* d_in, const int* in_sizes, int n_in,
                              void* d_out, int out_size, void* d_ws,
                              size_t ws_size, hipStream_t stream) {
  char* ws = (char*)d_ws;
  int*   flag = (int*)(ws + 0);
  __hip_bfloat16* MT = (__hip_bfloat16*)(ws + 1024);       // 8 KB
  float* u    = (float*)(ws + 9216);
  float* w_   = (float*)(ws + 9728);
  float* c_   = (float*)(ws + 10240);
  __hip_bfloat16* wvT = (__hip_bfloat16*)(ws + 32768);     // 64 KB
  __hip_bfloat16* xc  = (__hip_bfloat16*)(ws + 131072);    // 4 MB
  __hip_bfloat16* y   = (__hip_bfloat16*)(ws + 4325376);   // 4 MB
  float* qb = (float*)(ws + 8519680);                       // 128 KB
  float* kb = (float*)(ws + 8650752);                       // 128 KB
  __hip_bfloat16* xT = (__hip_bfloat16*)(ws + 8781824);    // 4 MB
  // total ws use: ~12.4 MB

  dtype_probe<<<1, 64, 0, stream>>>(d_in[1], flag);
  prep_kernel<<<81, 256, 0, stream>>>(d_in[1], d_in[3], d_in[5], d_in[2],
                                      d_in[4], MT, u, w_, c_, wvT, flag);
  proj_kernel<<<512, 256, 0, stream>>>(d_in[0], MT, u, w_, c_, xc, y, qb, kb,
                                       xT, flag);
  attn_kernel<<<512, 256, 0, stream>>>(xc, y, qb, kb, xT, wvT, d_in[6], d_out,
                                       flag);
}